// Round 6
// baseline (7645.614 us; speedup 1.0000x reference)
//
#include <hip/hip_runtime.h>
#include <hip/hip_bf16.h>

typedef __bf16 bf16x8 __attribute__((ext_vector_type(8)));
typedef float f32x4 __attribute__((ext_vector_type(4)));
typedef unsigned int u32;
typedef u32 u32x4 __attribute__((ext_vector_type(4)));

#define MFMA_B16(a,b,c) __builtin_amdgcn_mfma_f32_16x16x32_bf16((a),(b),(c),0,0,0)

// Tsit5 coefficients
#define A21f 0.161f
#define A31f (-0.008480655492356989f)
#define A32f 0.335480655492357f
#define A41f 2.8971530571054935f
#define A42f (-6.359448489975075f)
#define A43f 4.3622954328695815f
#define A51f 5.325864828439257f
#define A52f (-11.748883564062828f)
#define A53f 7.4955393428898365f
#define A54f (-0.09249506636175525f)
#define A61f 5.86145544294642f
#define A62f (-12.92096931784711f)
#define A63f 8.159367898576159f
#define A64f (-0.071584973281401f)
#define A65f (-0.028269050394068383f)
#define B1f 0.09646076681806523f
#define B2f 0.01f
#define B3f 0.4798896504144996f
#define B4f 1.379008574103742f
#define B5f (-3.290069515436081f)
#define B6f 2.324710524099774f

constexpr int T_SAVE = 128;
constexpr int DIM = 64;
constexpr int HID = 256;

__device__ __forceinline__ float fast_exp2(float x){
#if __has_builtin(__builtin_amdgcn_exp2f)
  return __builtin_amdgcn_exp2f(x);
#else
  return exp2f(x);
#endif
}
__device__ __forceinline__ float fast_rcp(float x){
#if __has_builtin(__builtin_amdgcn_rcpf)
  return __builtin_amdgcn_rcpf(x);
#else
  return 1.0f / x;
#endif
}
__device__ __forceinline__ float tanh_fast(float x){
  float t = fast_exp2(x * 2.8853900817779268f);
  return 1.0f - 2.0f * fast_rcp(t + 1.0f);
}
__device__ __forceinline__ f32x4 splat4(float x){ return f32x4{x,x,x,x}; }

// pack: low16 = hi-bf16 (mantissa truncation), high16 = lo-bf16 (RNE of residual)
__device__ __forceinline__ u32 pack_hl(float x){
  u32 xu = __float_as_uint(x);
  float lo = x - __uint_as_float(xu & 0xFFFF0000u);
  __bf16 lb = (__bf16)lo;
  unsigned short ls; __builtin_memcpy(&ls, &lb, 2);
  return ((u32)ls << 16) | (xu >> 16);
}
// 8 packed dwords (ascending k) -> hi-frag and lo-frag bf16x8
__device__ __forceinline__ void unpack2(const u32* p, bf16x8& ah, bf16x8& al){
  union { u32 d[4]; bf16x8 v; } H, L;
#pragma unroll
  for (int j = 0; j < 4; ++j) {
    H.d[j] = __builtin_amdgcn_perm(p[2*j+1], p[2*j], 0x05040100u);
    L.d[j] = __builtin_amdgcn_perm(p[2*j+1], p[2*j], 0x07060302u);
  }
  ah = H.v; al = L.v;
}

// block address: 4-dword block (row, kq) within a K-slice.
// bphys%8 = (row&7)^(kq&7): per-8-lane-permutation on reads (kq=2g+m, row=c),
// and writes spread 32 banks with only a free 2-way alias.
__device__ __forceinline__ int bphys(int row, int kq){
  return kq*16 + (row & 8) + ((row & 7) ^ (kq & 7));
}

// 8 waves (512 thr)/block, 16 rows/block, 2 waves/SIMD, 2 barriers/feval.
// Waves 0-3 ("state", v=w): own RK state + output dims v*16+c; write packed Y;
//   compute layer2 FULL K=256 for col-tile v -> kout in-register (no exchange).
// Waves 4-7 ("mlp", v=w-4): read Y, compute layer1 tiles {4v..4v+3} + tanh,
//   write packed H. No RK state, no global I/O.
__global__ __launch_bounds__(512, 2)
void node_tsit5_kernel(const float* __restrict__ y0, const float* __restrict__ ts,
                       const float* __restrict__ W1g, const float* __restrict__ b1g,
                       const float* __restrict__ W2g, const float* __restrict__ b2g,
                       const int* __restrict__ nsub_p, float* __restrict__ out)
{
  const int tid = (int)threadIdx.x;
  const int w   = tid >> 6;   // wave 0..7
  const int l   = tid & 63;
  const int c   = l & 15;
  const int g   = l >> 4;
  const bool state = (w < 4);
  const int v   = state ? w : (w - 4);
  const int rowbase = (int)blockIdx.x * 16;

  __shared__ __align__(16) u32 Yp[1024];   // 2 slices x 512 dwords
  __shared__ __align__(16) u32 Hp[4096];   // 8 slices x 512 dwords
  __shared__ float ts_s[T_SAVE];

  if (tid < T_SAVE) ts_s[tid] = ts[tid];

  const int nsub = nsub_p[0];

  // ---- role-unioned weight fragments (hi/lo split), 16 x bf16x8 = 64 VGPR ----
  // state:  wf[ks*2 + p]          : W2 slice ks (0..7), p=0 hi / 1 lo
  // mlp:    wf[t*4 + sl*2 + p]    : W1 tile t (0..3), slice sl (0..1)
  bf16x8 wf[16];
  float bias[4];
  if (state) {
#pragma unroll
    for (int ks = 0; ks < 8; ++ks)
#pragma unroll
      for (int j = 0; j < 8; ++j) {
        float val = W2g[(ks*32 + g*8 + j)*DIM + (v*16 + c)];
        __bf16 hi = (__bf16)val;
        wf[ks*2    ][j] = hi;
        wf[ks*2 + 1][j] = (__bf16)(val - (float)hi);
      }
    bias[0] = b2g[v*16 + c];
    bias[1] = bias[2] = bias[3] = 0.f;
  } else {
#pragma unroll
    for (int t = 0; t < 4; ++t) {
      const int col = (v*4 + t)*16 + c;
#pragma unroll
      for (int sl = 0; sl < 2; ++sl)
#pragma unroll
        for (int j = 0; j < 8; ++j) {
          float val = W1g[(sl*32 + g*8 + j)*HID + col];
          __bf16 hi = (__bf16)val;
          wf[t*4 + sl*2    ][j] = hi;
          wf[t*4 + sl*2 + 1][j] = (__bf16)(val - (float)hi);
        }
      bias[t] = b1g[col];
    }
  }

  // ---- LDS addresses ----
  // reads (both roles): lane (c,g) fetches blocks kq=2g, 2g+1 of each slice
  const int rdw0 = bphys(c, 2*g    ) * 4;
  const int rdw1 = bphys(c, 2*g + 1) * 4;
  // state Y-writes: value (row=4g+s, d=v*16+c)
  int yw[4];
#pragma unroll
  for (int s = 0; s < 4; ++s) {
    const int kq = (v & 1)*4 + (c >> 2);
    yw[s] = ((v >> 1)*512) + bphys(4*g + s, kq)*4 + (c & 3);
  }
  // mlp H-writes: tile T=v*4+t, value (row=4g+r, hid=T*16+c)
  int hw[4][4];
  if (!state) {
#pragma unroll
    for (int t = 0; t < 4; ++t) {
      const int T = v*4 + t;
      const int kq = (T & 1)*4 + (c >> 2);
#pragma unroll
      for (int r = 0; r < 4; ++r)
        hw[t][r] = ((T >> 1)*512) + bphys(4*g + r, kq)*4 + (c & 3);
    }
  }

  // ---- initial state (state waves); emit t=0 ----
  const int d_ = v*16 + c;
  f32x4 y4 = {0.f,0.f,0.f,0.f};
  if (state) {
#pragma unroll
    for (int s = 0; s < 4; ++s) {
      int row = rowbase + 4*g + s;
      y4[s] = y0[row*DIM + d_];
      out[(size_t)row*(T_SAVE*DIM) + d_] = y4[s];
    }
  }
  __syncthreads();   // ts_s ready

  f32x4 ysv = y4;

  auto feval = [&]() -> f32x4 {
    if (state) {
#pragma unroll
      for (int s = 0; s < 4; ++s) Yp[yw[s]] = pack_hl(ysv[s]);
    }
    __syncthreads();                       // bar1: Y ready
    if (!state) {
      u32 py[2][8];
      *(u32x4*)&py[0][0] = *(const u32x4*)&Yp[rdw0];
      *(u32x4*)&py[0][4] = *(const u32x4*)&Yp[rdw1];
      *(u32x4*)&py[1][0] = *(const u32x4*)&Yp[512 + rdw0];
      *(u32x4*)&py[1][4] = *(const u32x4*)&Yp[512 + rdw1];
      bf16x8 ah[2], al[2];
      unpack2(py[0], ah[0], al[0]);
      unpack2(py[1], ah[1], al[1]);
#pragma unroll
      for (int t = 0; t < 4; ++t) {
        f32x4 a0 = {0.f,0.f,0.f,0.f}, a1 = {0.f,0.f,0.f,0.f};
        a0 = MFMA_B16(ah[0], wf[t*4 + 0], a0);
        a1 = MFMA_B16(ah[1], wf[t*4 + 2], a1);
        a0 = MFMA_B16(ah[0], wf[t*4 + 1], a0);
        a1 = MFMA_B16(ah[1], wf[t*4 + 3], a1);
        a0 = MFMA_B16(al[0], wf[t*4 + 0], a0);
        a1 = MFMA_B16(al[1], wf[t*4 + 2], a1);
        f32x4 ht = a0 + a1;
#pragma unroll
        for (int r = 0; r < 4; ++r)
          Hp[hw[t][r]] = pack_hl(tanh_fast(ht[r] + bias[t]));
      }
    }
    __syncthreads();                       // bar2: H ready
    f32x4 ret = {0.f,0.f,0.f,0.f};
    if (state) {
      u32 ph[8][8];
#pragma unroll
      for (int ks = 0; ks < 8; ++ks) {
        *(u32x4*)&ph[ks][0] = *(const u32x4*)&Hp[ks*512 + rdw0];
        *(u32x4*)&ph[ks][4] = *(const u32x4*)&Hp[ks*512 + rdw1];
      }
      f32x4 aA = {0.f,0.f,0.f,0.f}, aB = {0.f,0.f,0.f,0.f}, aC = {0.f,0.f,0.f,0.f};
#pragma unroll
      for (int ks = 0; ks < 8; ++ks) {
        bf16x8 ah, al;
        unpack2(ph[ks], ah, al);
        aA = MFMA_B16(ah, wf[ks*2    ], aA);
        aB = MFMA_B16(ah, wf[ks*2 + 1], aB);
        aC = MFMA_B16(al, wf[ks*2    ], aC);
      }
      ret = (aA + aB) + aC + splat4(bias[0]);
    }
    return ret;
  };

  for (int iv = 0; iv < T_SAVE-1; ++iv) {
    const float h = (ts_s[iv+1] - ts_s[iv]) / (float)nsub;
    const f32x4 h4 = splat4(h);
    for (int sub = 0; sub < nsub; ++sub) {
      f32x4 k1 = feval();
      if (state) ysv = y4 + h4 * (splat4(A21f) * k1);
      f32x4 k2 = feval();
      if (state) {
        f32x4 t = splat4(A31f)*k1 + splat4(A32f)*k2;
        ysv = y4 + h4 * t;
      }
      f32x4 k3 = feval();
      if (state) {
        f32x4 t = splat4(A41f)*k1 + splat4(A42f)*k2 + splat4(A43f)*k3;
        ysv = y4 + h4 * t;
      }
      f32x4 k4 = feval();
      if (state) {
        f32x4 t = splat4(A51f)*k1 + splat4(A52f)*k2 + splat4(A53f)*k3
                + splat4(A54f)*k4;
        ysv = y4 + h4 * t;
      }
      f32x4 k5 = feval();
      if (state) {
        f32x4 t = splat4(A61f)*k1 + splat4(A62f)*k2 + splat4(A63f)*k3
                + splat4(A64f)*k4 + splat4(A65f)*k5;
        ysv = y4 + h4 * t;
      }
      f32x4 k6 = feval();
      if (state) {
        f32x4 t = splat4(B1f)*k1 + splat4(B2f)*k2 + splat4(B3f)*k3
                + splat4(B4f)*k4 + splat4(B5f)*k5 + splat4(B6f)*k6;
        y4 = y4 + h4 * t;
        ysv = y4;
      }
    }
    if (state) {
#pragma unroll
      for (int s = 0; s < 4; ++s) {
        int row = rowbase + 4*g + s;
        out[(size_t)row*(T_SAVE*DIM) + (size_t)(iv+1)*DIM + d_] = y4[s];
      }
    }
  }
}

extern "C" void kernel_launch(void* const* d_in, const int* in_sizes, int n_in,
                              void* d_out, int out_size, void* d_ws, size_t ws_size,
                              hipStream_t stream) {
  const float* y0 = (const float*)d_in[0];
  const float* ts = (const float*)d_in[1];
  const float* W1 = (const float*)d_in[2];
  const float* b1 = (const float*)d_in[3];
  const float* W2 = (const float*)d_in[4];
  const float* b2 = (const float*)d_in[5];
  const int* nsub = (const int*)d_in[6];
  float* out = (float*)d_out;

  const int Bnum = in_sizes[0] / DIM;       // 4096
  const int nblocks = Bnum / 16;            // 256 workgroups, one per CU
  node_tsit5_kernel<<<nblocks, 512, 0, stream>>>(y0, ts, W1, b1, W2, b2, nsub, out);
}